// Round 1
// baseline (464.761 us; speedup 1.0000x reference)
//
#include <hip/hip_runtime.h>
#include <math.h>

// Sizes fixed by the reference: B=512, T=1024, D_IN=D_OUT=64, H=256.
#define HDIM 256
#define DDIM 64
#define BROWS 512
#define TSTEPS 1024
// Augmented rows: 65 weight rows (t-row + 64 state rows) + 1 bias row.
#define AROWS 66

// ---- Setup: compose the linear MLP into one 66x64 affine map ----
// out1[r][c] = (r<65 ? W0[r] : b0) @ W1[:,c]  (+ b1[c] if r==65)
__global__ void compose1(const float* __restrict__ W0, const float* __restrict__ b0,
                         const float* __restrict__ W1, const float* __restrict__ b1,
                         float* __restrict__ out1) {
    int r = blockIdx.x;    // 0..65
    int c = threadIdx.x;   // 0..255
    const float* arow = (r < 65) ? (W0 + r * HDIM) : b0;
    float acc = (r == 65) ? b1[c] : 0.0f;
    for (int h = 0; h < HDIM; ++h)
        acc = fmaf(arow[h], W1[h * HDIM + c], acc);
    out1[r * HDIM + c] = acc;
}

__global__ void compose2(const float* __restrict__ in1,
                         const float* __restrict__ W2, const float* __restrict__ b2,
                         float* __restrict__ out2) {
    int r = blockIdx.x, c = threadIdx.x;
    const float* arow = in1 + r * HDIM;
    float acc = (r == 65) ? b2[c] : 0.0f;
    for (int h = 0; h < HDIM; ++h)
        acc = fmaf(arow[h], W2[h * HDIM + c], acc);
    out2[r * HDIM + c] = acc;
}

__global__ void compose3(const float* __restrict__ in2,
                         const float* __restrict__ W3, const float* __restrict__ b3,
                         float* __restrict__ out3) {
    int r = blockIdx.x, c = threadIdx.x;   // c 0..63
    const float* arow = in2 + r * HDIM;
    float acc = (r == 65) ? b3[c] : 0.0f;
    for (int h = 0; h < HDIM; ++h)
        acc = fmaf(arow[h], W3[h * DDIM + c], acc);
    out3[r * DDIM + c] = acc;
}

// ---- Main scan: one wave per batch row, lane = output dim ----
// y_new[d] = y[d] + factor_k * tanh(b_eff[d] + t_k*w_t[d] + sum_j y[j]*Weff[j][d])
__launch_bounds__(64)
__global__ void fode_scan(const float* __restrict__ x, const float* __restrict__ t,
                          const float* __restrict__ Weff,   // 66 x 64 composed
                          float* __restrict__ out) {
    const int b = blockIdx.x;
    const int d = threadIdx.x;   // 0..63

    __shared__ float ylds[DDIM];

    // Weff column for this lane: W[j] = Weff[(1+j)*64 + d]
    float W[DDIM];
#pragma unroll
    for (int j = 0; j < DDIM; ++j)
        W[j] = Weff[(1 + j) * DDIM + d];
    const float wt   = Weff[d];                 // t-coefficient row
    const float bias = Weff[65 * DDIM + d];     // folded bias row

    float y = x[b * DDIM + d];
    size_t obase = (size_t)b * TSTEPS * DDIM;
    out[obase + d] = y;                          // solution[:,0,:] = x
    ylds[d] = y;
    __syncthreads();

    const float invG = 0.56418958354775628695f;  // 1/Gamma(0.5)

    for (int k = 0; k < TSTEPS - 1; ++k) {
        float tk = t[k];
        float dt = t[k + 1] - tk;
        float factor = sqrtf(dt) * invG;

        float a0 = fmaf(tk, wt, bias), a1 = 0.f, a2 = 0.f, a3 = 0.f;
#pragma unroll
        for (int c = 0; c < 16; ++c) {
            float4 yv = *reinterpret_cast<const float4*>(&ylds[c * 4]);
            a0 = fmaf(yv.x, W[c * 4 + 0], a0);
            a1 = fmaf(yv.y, W[c * 4 + 1], a1);
            a2 = fmaf(yv.z, W[c * 4 + 2], a2);
            a3 = fmaf(yv.w, W[c * 4 + 3], a3);
        }
        float s = (a0 + a1) + (a2 + a3);

        // fast tanh: 1 - 2/(exp(2s)+1); saturates correctly for |s| large
        float e  = __expf(2.0f * s);
        float th = 1.0f - 2.0f / (e + 1.0f);

        y = fmaf(factor, th, y);
        out[obase + (size_t)(k + 1) * DDIM + d] = y;

        ylds[d] = y;          // reads above are same-wave, in program order
        __syncthreads();      // 1-wave block: cheap; guards next iter's reads
    }
}

extern "C" void kernel_launch(void* const* d_in, const int* in_sizes, int n_in,
                              void* d_out, int out_size, void* d_ws, size_t ws_size,
                              hipStream_t stream) {
    const float* x  = (const float*)d_in[0];
    const float* t  = (const float*)d_in[1];
    const float* W0 = (const float*)d_in[2];
    const float* b0 = (const float*)d_in[3];
    const float* W1 = (const float*)d_in[4];
    const float* b1 = (const float*)d_in[5];
    const float* W2 = (const float*)d_in[6];
    const float* b2 = (const float*)d_in[7];
    const float* W3 = (const float*)d_in[8];
    const float* b3 = (const float*)d_in[9];
    float* out = (float*)d_out;

    float* buf1 = (float*)d_ws;            // 66*256 floats
    float* buf2 = buf1 + AROWS * HDIM;     // 66*256 floats
    float* buf3 = buf2 + AROWS * HDIM;     // 66*64 floats

    compose1<<<AROWS, HDIM, 0, stream>>>(W0, b0, W1, b1, buf1);
    compose2<<<AROWS, HDIM, 0, stream>>>(buf1, W2, b2, buf2);
    compose3<<<AROWS, DDIM, 0, stream>>>(buf2, W3, b3, buf3);
    fode_scan<<<BROWS, DDIM, 0, stream>>>(x, t, buf3, out);
}

// Round 2
// 387.982 us; speedup vs baseline: 1.1979x; 1.1979x over previous
//
#include <hip/hip_runtime.h>
#include <math.h>

// Sizes fixed by the reference: B=512, T=1024, D_IN=D_OUT=64, H=256.
#define HDIM 256
#define DDIM 64
#define BROWS 512
#define TSTEPS 1024
// Augmented rows: 65 weight rows (t-row + 64 state rows) + 1 bias row.
#define AROWS 66

// ---- Setup: compose the linear MLP into one 66x64 affine map ----
__global__ void compose1(const float* __restrict__ W0, const float* __restrict__ b0,
                         const float* __restrict__ W1, const float* __restrict__ b1,
                         float* __restrict__ out1) {
    int r = blockIdx.x;    // 0..65
    int c = threadIdx.x;   // 0..255
    const float* arow = (r < 65) ? (W0 + r * HDIM) : b0;
    float acc = (r == 65) ? b1[c] : 0.0f;
    for (int h = 0; h < HDIM; ++h)
        acc = fmaf(arow[h], W1[h * HDIM + c], acc);
    out1[r * HDIM + c] = acc;
}

__global__ void compose2(const float* __restrict__ in1,
                         const float* __restrict__ W2, const float* __restrict__ b2,
                         float* __restrict__ out2) {
    int r = blockIdx.x, c = threadIdx.x;
    const float* arow = in1 + r * HDIM;
    float acc = (r == 65) ? b2[c] : 0.0f;
    for (int h = 0; h < HDIM; ++h)
        acc = fmaf(arow[h], W2[h * HDIM + c], acc);
    out2[r * HDIM + c] = acc;
}

__global__ void compose3(const float* __restrict__ in2,
                         const float* __restrict__ W3, const float* __restrict__ b3,
                         float* __restrict__ out3) {
    int r = blockIdx.x, c = threadIdx.x;   // c 0..63
    const float* arow = in2 + r * HDIM;
    float acc = (r == 65) ? b3[c] : 0.0f;
    for (int h = 0; h < HDIM; ++h)
        acc = fmaf(arow[h], W3[h * DDIM + c], acc);
    out3[r * DDIM + c] = acc;
}

// ---- Main scan: one wave per batch row, lane = output dim ----
// y_new[d] = y[d] + factor_k * tanh(b_eff[d] + t_k*w_t[d] + sum_j y[j]*Weff[j][d])
//
// Single-wave block. Cross-lane y broadcast goes through LDS with a RAW
// s_barrier (no vmcnt drain — __syncthreads would stall on the fire-and-
// forget HBM store every step). HW DS ordering is in-order per wave, so
// ds_write -> ds_read needs no waitcnt; the barrier is only a compiler
// fence so LDS isn't register-cached across iterations.
__launch_bounds__(64)
__global__ void fode_scan(const float* __restrict__ x, const float* __restrict__ t,
                          const float* __restrict__ Weff,   // 66 x 64 composed
                          float* __restrict__ out) {
    const int b = blockIdx.x;
    const int d = threadIdx.x;   // 0..63

    __shared__ float ylds[DDIM];

    // Weff column for this lane: W[j] = Weff[(1+j)*64 + d]
    float W[DDIM];
#pragma unroll
    for (int j = 0; j < DDIM; ++j)
        W[j] = Weff[(1 + j) * DDIM + d];
    const float wt   = Weff[d];                 // t-coefficient row
    const float bias = Weff[65 * DDIM + d];     // folded bias row

    float y = x[b * DDIM + d];
    size_t obase = (size_t)b * TSTEPS * DDIM;
    out[obase + d] = y;                          // solution[:,0,:] = x
    ylds[d] = y;
    __builtin_amdgcn_s_barrier();

    const float invG = 0.56418958354775628695f;  // 1/Gamma(0.5)

    for (int k = 0; k < TSTEPS - 1; ++k) {
        float tk = t[k];
        float dt = t[k + 1] - tk;
        float factor = sqrtf(dt) * invG;         // off-chain: overlaps LDS latency

        float a0 = fmaf(tk, wt, bias), a1 = 0.f, a2 = 0.f, a3 = 0.f;
#pragma unroll
        for (int c = 0; c < 16; ++c) {
            float4 yv = *reinterpret_cast<const float4*>(&ylds[c * 4]);
            a0 = fmaf(yv.x, W[c * 4 + 0], a0);
            a1 = fmaf(yv.y, W[c * 4 + 1], a1);
            a2 = fmaf(yv.z, W[c * 4 + 2], a2);
            a3 = fmaf(yv.w, W[c * 4 + 3], a3);
        }
        float s = (a0 + a1) + (a2 + a3);

        // tanh(s) = 1 - 2/(exp(2s)+1); rcp instead of full-precision div
        float e  = __expf(2.0f * s);
        float th = fmaf(-2.0f, __builtin_amdgcn_rcpf(e + 1.0f), 1.0f);

        y = fmaf(factor, th, y);

        ylds[d] = y;                              // LDS first: next iter's input
        out[obase + (size_t)(k + 1) * DDIM + d] = y;  // fire-and-forget
        __builtin_amdgcn_s_barrier();             // compiler fence; no vmcnt drain
    }
}

extern "C" void kernel_launch(void* const* d_in, const int* in_sizes, int n_in,
                              void* d_out, int out_size, void* d_ws, size_t ws_size,
                              hipStream_t stream) {
    const float* x  = (const float*)d_in[0];
    const float* t  = (const float*)d_in[1];
    const float* W0 = (const float*)d_in[2];
    const float* b0 = (const float*)d_in[3];
    const float* W1 = (const float*)d_in[4];
    const float* b1 = (const float*)d_in[5];
    const float* W2 = (const float*)d_in[6];
    const float* b2 = (const float*)d_in[7];
    const float* W3 = (const float*)d_in[8];
    const float* b3 = (const float*)d_in[9];
    float* out = (float*)d_out;

    float* buf1 = (float*)d_ws;            // 66*256 floats
    float* buf2 = buf1 + AROWS * HDIM;     // 66*256 floats
    float* buf3 = buf2 + AROWS * HDIM;     // 66*64 floats

    compose1<<<AROWS, HDIM, 0, stream>>>(W0, b0, W1, b1, buf1);
    compose2<<<AROWS, HDIM, 0, stream>>>(buf1, W2, b2, buf2);
    compose3<<<AROWS, DDIM, 0, stream>>>(buf2, W3, b3, buf3);
    fode_scan<<<BROWS, DDIM, 0, stream>>>(x, t, buf3, out);
}

// Round 3
// 336.933 us; speedup vs baseline: 1.3794x; 1.1515x over previous
//
#include <hip/hip_runtime.h>
#include <math.h>

// Sizes fixed by the reference: B=512, T=1024, D_IN=D_OUT=64, H=256.
#define HDIM 256
#define DDIM 64
#define BROWS 512
#define TSTEPS 1024
// Augmented rows: 65 weight rows (t-row + 64 state rows) + 1 bias row.
#define AROWS 66

// ---- Setup: compose the linear MLP into one 66x64 affine map ----
__global__ void compose1(const float* __restrict__ W0, const float* __restrict__ b0,
                         const float* __restrict__ W1, const float* __restrict__ b1,
                         float* __restrict__ out1) {
    int r = blockIdx.x;    // 0..65
    int c = threadIdx.x;   // 0..255
    const float* arow = (r < 65) ? (W0 + r * HDIM) : b0;
    float acc = (r == 65) ? b1[c] : 0.0f;
    for (int h = 0; h < HDIM; ++h)
        acc = fmaf(arow[h], W1[h * HDIM + c], acc);
    out1[r * HDIM + c] = acc;
}

__global__ void compose2(const float* __restrict__ in1,
                         const float* __restrict__ W2, const float* __restrict__ b2,
                         float* __restrict__ out2) {
    int r = blockIdx.x, c = threadIdx.x;
    const float* arow = in1 + r * HDIM;
    float acc = (r == 65) ? b2[c] : 0.0f;
    for (int h = 0; h < HDIM; ++h)
        acc = fmaf(arow[h], W2[h * HDIM + c], acc);
    out2[r * HDIM + c] = acc;
}

__global__ void compose3(const float* __restrict__ in2,
                         const float* __restrict__ W3, const float* __restrict__ b3,
                         float* __restrict__ out3) {
    int r = blockIdx.x, c = threadIdx.x;   // c 0..63
    const float* arow = in2 + r * HDIM;
    float acc = (r == 65) ? b3[c] : 0.0f;
    for (int h = 0; h < HDIM; ++h)
        acc = fmaf(arow[h], W3[h * DDIM + c], acc);
    out3[r * DDIM + c] = acc;
}

// ---- Main scan: one wave per batch row, lane = output dim ----
// y_new[d] = y[d] + factor_k * tanh(b_eff[d] + t_k*w_t[d] + sum_j y[j]*Weff[j][d])
//
// Single-wave block, NO barriers, NO global loads in the loop:
//  - (t_k, factor_k) pairs staged into LDS once; prefetched 1 step ahead.
//  - y broadcast through LDS; DS ops from one wave execute in order, and the
//    compiler cannot reorder aliasing LDS accesses, so a compiler-only fence
//    replaces s_barrier.
//  - the only VMEM op in the loop is the out-store, which is never waited on
//    (previous version waited vmcnt(0) through the in-order counter because
//    the per-step t[k] load was issued after the store — ~400 cyc/step lost).
__launch_bounds__(64)
__global__ void fode_scan(const float* __restrict__ x, const float* __restrict__ t,
                          const float* __restrict__ Weff,   // 66 x 64 composed
                          float* __restrict__ out) {
    const int b = blockIdx.x;
    const int d = threadIdx.x;   // 0..63

    __shared__ float  ylds[DDIM];
    __shared__ float2 plds[TSTEPS];   // (t_k, factor_k); entry TSTEPS-1 unused

    const float invG = 0.56418958354775628695f;  // 1/Gamma(0.5)

    // Stage per-step params: coalesced, once per block (t is 4 KB, L2-hot).
    for (int i = d; i < TSTEPS - 1; i += DDIM) {
        float t0 = t[i];
        float t1 = t[i + 1];
        plds[i] = make_float2(t0, sqrtf(t1 - t0) * invG);
    }

    // Weff column for this lane: W[j] = Weff[(1+j)*64 + d]
    float W[DDIM];
#pragma unroll
    for (int j = 0; j < DDIM; ++j)
        W[j] = Weff[(1 + j) * DDIM + d];
    const float wt   = Weff[d];                 // t-coefficient row
    const float bias = Weff[65 * DDIM + d];     // folded bias row

    float y = x[b * DDIM + d];
    float* op = out + (size_t)b * TSTEPS * DDIM + d;
    *op = y;                                     // solution[:,0,:] = x
    ylds[d] = y;
    asm volatile("" ::: "memory");               // compiler fence (1-wave block)

    float2 prm = plds[0];                        // same-wave DS: in-order, no wait

    for (int k = 0; k < TSTEPS - 1; ++k) {
        float2 prm_next = plds[k + 1];           // prefetch; garbage at last iter, unused

        float a0 = fmaf(prm.x, wt, bias), a1 = 0.f, a2 = 0.f, a3 = 0.f;
#pragma unroll
        for (int c = 0; c < 16; ++c) {
            float4 yv = *reinterpret_cast<const float4*>(&ylds[c * 4]);
            a0 = fmaf(yv.x, W[c * 4 + 0], a0);
            a1 = fmaf(yv.y, W[c * 4 + 1], a1);
            a2 = fmaf(yv.z, W[c * 4 + 2], a2);
            a3 = fmaf(yv.w, W[c * 4 + 3], a3);
        }
        float s = (a0 + a1) + (a2 + a3);

        // tanh(s) = 1 - 2/(exp(2s)+1), via raw v_exp_f32 + v_rcp_f32
        float e  = __builtin_amdgcn_exp2f(s * 2.88539008177792681472f); // 2*log2(e)
        float th = fmaf(-2.0f, __builtin_amdgcn_rcpf(e + 1.0f), 1.0f);

        y = fmaf(prm.y, th, y);

        asm volatile("" ::: "memory");
        ylds[d] = y;                              // next iter's input (in-order DS)
        op += DDIM;
        *op = y;                                  // fire-and-forget, never waited
        asm volatile("" ::: "memory");
        prm = prm_next;
    }
}

extern "C" void kernel_launch(void* const* d_in, const int* in_sizes, int n_in,
                              void* d_out, int out_size, void* d_ws, size_t ws_size,
                              hipStream_t stream) {
    const float* x  = (const float*)d_in[0];
    const float* t  = (const float*)d_in[1];
    const float* W0 = (const float*)d_in[2];
    const float* b0 = (const float*)d_in[3];
    const float* W1 = (const float*)d_in[4];
    const float* b1 = (const float*)d_in[5];
    const float* W2 = (const float*)d_in[6];
    const float* b2 = (const float*)d_in[7];
    const float* W3 = (const float*)d_in[8];
    const float* b3 = (const float*)d_in[9];
    float* out = (float*)d_out;

    float* buf1 = (float*)d_ws;            // 66*256 floats
    float* buf2 = buf1 + AROWS * HDIM;     // 66*256 floats
    float* buf3 = buf2 + AROWS * HDIM;     // 66*64 floats

    compose1<<<AROWS, HDIM, 0, stream>>>(W0, b0, W1, b1, buf1);
    compose2<<<AROWS, HDIM, 0, stream>>>(buf1, W2, b2, buf2);
    compose3<<<AROWS, DDIM, 0, stream>>>(buf2, W3, b3, buf3);
    fode_scan<<<BROWS, DDIM, 0, stream>>>(x, t, buf3, out);
}

// Round 4
// 323.116 us; speedup vs baseline: 1.4384x; 1.0428x over previous
//
#include <hip/hip_runtime.h>
#include <math.h>

// Sizes fixed by the reference: B=512, T=1024, D_IN=D_OUT=64, H=256.
#define HDIM 256
#define DDIM 64
#define BROWS 512
#define TSTEPS 1024
// Augmented rows: 65 weight rows (t-row + 64 state rows) + 1 bias row.
#define AROWS 66

// ---- Setup: compose the linear MLP into one 66x64 affine map ----
__global__ void compose1(const float* __restrict__ W0, const float* __restrict__ b0,
                         const float* __restrict__ W1, const float* __restrict__ b1,
                         float* __restrict__ out1) {
    int r = blockIdx.x;    // 0..65
    int c = threadIdx.x;   // 0..255
    const float* arow = (r < 65) ? (W0 + r * HDIM) : b0;
    float acc = (r == 65) ? b1[c] : 0.0f;
    for (int h = 0; h < HDIM; ++h)
        acc = fmaf(arow[h], W1[h * HDIM + c], acc);
    out1[r * HDIM + c] = acc;
}

__global__ void compose2(const float* __restrict__ in1,
                         const float* __restrict__ W2, const float* __restrict__ b2,
                         float* __restrict__ out2) {
    int r = blockIdx.x, c = threadIdx.x;
    const float* arow = in1 + r * HDIM;
    float acc = (r == 65) ? b2[c] : 0.0f;
    for (int h = 0; h < HDIM; ++h)
        acc = fmaf(arow[h], W2[h * HDIM + c], acc);
    out2[r * HDIM + c] = acc;
}

__global__ void compose3(const float* __restrict__ in2,
                         const float* __restrict__ W3, const float* __restrict__ b3,
                         float* __restrict__ out3) {
    int r = blockIdx.x, c = threadIdx.x;   // c 0..63
    const float* arow = in2 + r * HDIM;
    float acc = (r == 65) ? b3[c] : 0.0f;
    for (int h = 0; h < HDIM; ++h)
        acc = fmaf(arow[h], W3[h * DDIM + c], acc);
    out3[r * DDIM + c] = acc;
}

// Broadcast y from lane j to all lanes via v_readlane (register file, no LDS).
__device__ __forceinline__ float bcast(float v, int lane) {
    return __uint_as_float(__builtin_amdgcn_readlane(__float_as_uint(v), lane));
}

// ---- Main scan: one wave per batch row, lane = output dim ----
// y_new[d] = y[d] + factor_k * tanh(b_eff[d] + t_k*w_t[d] + sum_j y[j]*Weff[j][d])
//
// Single-wave block. The per-step all-to-all y broadcast is done with 64
// v_readlane_b32 (constant lane index) feeding v_fma_f32 with an SGPR
// operand — zero DS ops on the critical path (round 2 showed the 16
// ds_read_b128 broadcast + write round-trip was ~580 of 765 cyc/step).
// Loop DS: one prefetched ds_read_b64 (params). Loop VMEM: one store,
// never waited on.
__launch_bounds__(64)
__global__ void fode_scan(const float* __restrict__ x, const float* __restrict__ t,
                          const float* __restrict__ Weff,   // 66 x 64 composed
                          float* __restrict__ out) {
    const int b = blockIdx.x;
    const int d = threadIdx.x;   // 0..63

    __shared__ float2 plds[TSTEPS];   // (t_k, factor_k); entry TSTEPS-1 unused

    const float invG = 0.56418958354775628695f;  // 1/Gamma(0.5)

    // Stage per-step params: coalesced, once per block (t is 4 KB, L2-hot).
    for (int i = d; i < TSTEPS - 1; i += DDIM) {
        float t0 = t[i];
        float t1 = t[i + 1];
        plds[i] = make_float2(t0, sqrtf(t1 - t0) * invG);
    }

    // Weff column for this lane: W[j] = Weff[(1+j)*64 + d]
    float W[DDIM];
#pragma unroll
    for (int j = 0; j < DDIM; ++j)
        W[j] = Weff[(1 + j) * DDIM + d];
    const float wt   = Weff[d];                 // t-coefficient row
    const float bias = Weff[65 * DDIM + d];     // folded bias row

    float y = x[b * DDIM + d];
    float* op = out + (size_t)b * TSTEPS * DDIM + d;
    *op = y;                                     // solution[:,0,:] = x

    float2 prm = plds[0];                        // same-wave DS: in-order

    for (int k = 0; k < TSTEPS - 1; ++k) {
        float2 prm_next = plds[k + 1];           // prefetch; garbage at last iter, unused

        float a0 = fmaf(prm.x, wt, bias), a1 = 0.f, a2 = 0.f, a3 = 0.f;
#pragma unroll
        for (int j = 0; j < DDIM; j += 4) {
            a0 = fmaf(bcast(y, j + 0), W[j + 0], a0);
            a1 = fmaf(bcast(y, j + 1), W[j + 1], a1);
            a2 = fmaf(bcast(y, j + 2), W[j + 2], a2);
            a3 = fmaf(bcast(y, j + 3), W[j + 3], a3);
        }
        float s = (a0 + a1) + (a2 + a3);

        // tanh(s) = 1 - 2/(exp(2s)+1), via raw v_exp_f32 + v_rcp_f32
        float e  = __builtin_amdgcn_exp2f(s * 2.88539008177792681472f); // 2*log2(e)
        float th = fmaf(-2.0f, __builtin_amdgcn_rcpf(e + 1.0f), 1.0f);

        y = fmaf(prm.y, th, y);

        op += DDIM;
        *op = y;                                  // fire-and-forget, never waited
        prm = prm_next;
    }
}

extern "C" void kernel_launch(void* const* d_in, const int* in_sizes, int n_in,
                              void* d_out, int out_size, void* d_ws, size_t ws_size,
                              hipStream_t stream) {
    const float* x  = (const float*)d_in[0];
    const float* t  = (const float*)d_in[1];
    const float* W0 = (const float*)d_in[2];
    const float* b0 = (const float*)d_in[3];
    const float* W1 = (const float*)d_in[4];
    const float* b1 = (const float*)d_in[5];
    const float* W2 = (const float*)d_in[6];
    const float* b2 = (const float*)d_in[7];
    const float* W3 = (const float*)d_in[8];
    const float* b3 = (const float*)d_in[9];
    float* out = (float*)d_out;

    float* buf1 = (float*)d_ws;            // 66*256 floats
    float* buf2 = buf1 + AROWS * HDIM;     // 66*256 floats
    float* buf3 = buf2 + AROWS * HDIM;     // 66*64 floats

    compose1<<<AROWS, HDIM, 0, stream>>>(W0, b0, W1, b1, buf1);
    compose2<<<AROWS, HDIM, 0, stream>>>(buf1, W2, b2, buf2);
    compose3<<<AROWS, DDIM, 0, stream>>>(buf2, W3, b3, buf3);
    fode_scan<<<BROWS, DDIM, 0, stream>>>(x, t, buf3, out);
}